// Round 6
// baseline (830.893 us; speedup 1.0000x reference)
//
#include <hip/hip_runtime.h>

// LSTMDecoder: B=4096, LATENT=128, SEQ=512, HID=32, OUT=64. f32 in/out.
// Round 6: transposed recurrence + permuted cell order => ZERO cross-lane
// traffic in the step loop (no LDS, no barrier, no shuffles).
//
// Key identities:
//  - gates^T[128x16] = W_hh[128x32] @ h^T[32x16]: A-frag = W_hh tiles (resident),
//    B-frag of h^T == A-frag of h (same physical layout: lane(kb,n) holds
//    h[n][k=kb*8+i]). One register octet `a` is B-operand for gates AND
//    A-operand for the normal-orientation projection y = h @ out_W^T.
//  - cell permutation sigma(kb*8 + jj*4 + r) = 4*kb + 16*jj + r applied to
//    W_hh cols, out_W cols, and the state's k-order. Gates-D gives lane(kb,n)
//    cells {4kb+16jj+r} of batch row n with i,f,g,o lane-local (tiles jj,2+jj,
//    4+jj,6+jj); those are EXACTLY the cells position kb*8+jj*4+r of the next
//    fragment needs. D->A transform = 8 in-lane f16 converts. Recurrence chain:
//    8 MFMAs -> activations -> pack. Fully serial-friendly.
//  - projection D layout == round-5's (row kb*4+r, col 16p+n_): same proven
//    store pattern (4x64B segments/instr), WRITE_SIZE exact.
//  - c state fp32 (8/lane); h carried f16 RNE (verified absmax = bf16 quantum).
// Grid: 256 single-wave blocks (16 batch rows each). Expected limiter: the
// 536 MB y-write HBM floor (~85 us).

#define B_SZ   4096
#define LATENT 128
#define SEQ    512
#define HID    32
#define OUT_N  64
#define ROWS   16
#define LSW    40   // h0 staging row stride (halves); 80 B rows, 8B-aligned chunks

typedef _Float16 f16x8 __attribute__((ext_vector_type(8)));
typedef _Float16 f16x4 __attribute__((ext_vector_type(4)));
typedef float    f32x4 __attribute__((ext_vector_type(4)));

__device__ __forceinline__ float fexp2(float x) { return __builtin_amdgcn_exp2f(x); }
__device__ __forceinline__ float frcp(float x)  { return __builtin_amdgcn_rcpf(x); }
__device__ __forceinline__ float sigm(float x) {
    return frcp(1.f + fexp2(-1.44269504088896341f * x));
}
__device__ __forceinline__ float tanh_f(float x) {
    return fmaf(-2.f, frcp(1.f + fexp2(2.88539008177792681f * x)), 1.f);
}

__global__ __launch_bounds__(64)
void lstm_tr(const float* __restrict__ z,
             const float* __restrict__ init_W,
             const float* __restrict__ init_b,
             const float* __restrict__ W_hh,
             const float* __restrict__ b_ih,
             const float* __restrict__ b_hh,
             const float* __restrict__ out_W,
             const float* __restrict__ out_b,
             float* __restrict__ y)
{
    __shared__ __align__(16) _Float16 hst[ROWS * LSW];

    const int lane = threadIdx.x;       // single wave
    const int n_   = lane & 15;         // batch-row within tile (B-col / A-row)
    const int kb   = lane >> 4;         // k-group / D row-group
    const int rbase = blockIdx.x * ROWS;

    // ---- resident W_hh A-frags (permuted cols) + per-reg bias C-frags ----
    // tile g: lane(kb,n_) reg i: W_hh[16g+n_][sigma(kb*8+i)],
    // sigma(kb*8+jj*4+rr) = 4kb+16jj+rr
    f16x8 wf[8];
    f32x4 bacc[8];
#pragma unroll
    for (int g = 0; g < 8; g++) {
        const float* row = W_hh + (size_t)(16 * g + n_) * HID;
        f16x8 v;
#pragma unroll
        for (int rr = 0; rr < 4; rr++) {
            v[rr]     = (_Float16)row[4 * kb + rr];
            v[4 + rr] = (_Float16)row[4 * kb + 16 + rr];
        }
        wf[g] = v;
        f32x4 b;
#pragma unroll
        for (int r = 0; r < 4; r++) {
            int G = 16 * g + 4 * kb + r;      // C[kb*4+r][n] = bias[G]
            b[r] = b_ih[G] + b_hh[G];
        }
        bacc[g] = b;
    }
    // out_W B-frags (permuted cols): tile p: lane reg i: out_W[16p+n_][sigma(kb*8+i)]
    f16x8 bow[4];
    f32x4 oacc[4];
#pragma unroll
    for (int p = 0; p < 4; p++) {
        const float* row = out_W + (size_t)(16 * p + n_) * HID;
        f16x8 v;
#pragma unroll
        for (int rr = 0; rr < 4; rr++) {
            v[rr]     = (_Float16)row[4 * kb + rr];
            v[4 + rr] = (_Float16)row[4 * kb + 16 + rr];
        }
        bow[p] = v;
        float b = out_b[16 * p + n_];
        oacc[p] = (f32x4){b, b, b, b};
    }

    // ---- h0 = z @ init_W^T + init_b (one-time fp32 dot, 8 cells/lane) ----
#pragma unroll
    for (int ii = 0; ii < 8; ii++) {
        int m = ii * 2 + (lane >> 5);
        int j = lane & 31;
        const float4* zp = (const float4*)(z + (size_t)(rbase + m) * LATENT);
        const float4* wp = (const float4*)(init_W + (size_t)j * LATENT);
        float acc = init_b[j];
#pragma unroll
        for (int k = 0; k < LATENT / 4; k++) {
            float4 a4 = zp[k], b4 = wp[k];
            acc = fmaf(a4.x, b4.x, acc); acc = fmaf(a4.y, b4.y, acc);
            acc = fmaf(a4.z, b4.z, acc); acc = fmaf(a4.w, b4.w, acc);
        }
        hst[m * LSW + j] = (_Float16)acc;
    }
    // initial state fragment: position kb*8 + jj*4 + rr <- h0[n_][4kb+16jj+rr]
    // (single wave: compiler's lgkmcnt tracking orders the ds write->read)
    f16x8 a;
    {
        f16x4 lo = *(const f16x4*)&hst[n_ * LSW + 4 * kb];
        f16x4 hi = *(const f16x4*)&hst[n_ * LSW + 4 * kb + 16];
#pragma unroll
        for (int r = 0; r < 4; r++) { a[r] = lo[r]; a[4 + r] = hi[r]; }
    }

    float c8[8];   // c for (row n_, cell 4kb+16jj+r), fp32
#pragma unroll
    for (int i = 0; i < 8; i++) c8[i] = 0.f;

    float* yb = y + (size_t)(rbase + kb * 4) * SEQ * OUT_N + n_;

    for (int t = 0; t < SEQ; t++) {
        // ---- gates^T: D[4kb+r][n_] of tile g = preact gate 16g+4kb+r, row n_ ----
        f32x4 acc[8];
#pragma unroll
        for (int g = 0; g < 8; g++)
            acc[g] = __builtin_amdgcn_mfma_f32_16x16x32_f16(wf[g], a, bacc[g], 0, 0, 0);

        // ---- lane-local activations + state update + in-lane repack to `a` ----
        f16x8 na;
#pragma unroll
        for (int jj = 0; jj < 2; jj++) {
#pragma unroll
            for (int r = 0; r < 4; r++) {
                float gi = sigm(acc[0 + jj][r]);
                float gf = sigm(acc[2 + jj][r]);
                float gg = tanh_f(acc[4 + jj][r]);
                float go = sigm(acc[6 + jj][r]);
                float cn = fmaf(gf, c8[jj * 4 + r], gi * gg);
                c8[jj * 4 + r] = cn;
                na[jj * 4 + r] = (_Float16)(go * tanh_f(cn));  // RNE
            }
        }
        a = na;

        // ---- projection of h_{t+1}: y[row 4kb+r][16p+n_] ----
        f32x4 py[4];
#pragma unroll
        for (int p = 0; p < 4; p++)
            py[p] = __builtin_amdgcn_mfma_f32_16x16x32_f16(a, bow[p], oacc[p], 0, 0, 0);

#pragma unroll
        for (int p = 0; p < 4; p++) {
#pragma unroll
            for (int r = 0; r < 4; r++)
                yb[(size_t)r * SEQ * OUT_N + (size_t)t * OUT_N + p * 16] = py[p][r];
        }
    }
}

extern "C" void kernel_launch(void* const* d_in, const int* in_sizes, int n_in,
                              void* d_out, int out_size, void* d_ws, size_t ws_size,
                              hipStream_t stream) {
    const float* z      = (const float*)d_in[0];
    const float* init_W = (const float*)d_in[1];
    const float* init_b = (const float*)d_in[2];
    // d_in[3] = W_ih: unused (x input is all zeros; only biases survive)
    const float* W_hh   = (const float*)d_in[4];
    const float* b_ih   = (const float*)d_in[5];
    const float* b_hh   = (const float*)d_in[6];
    const float* out_W  = (const float*)d_in[7];
    const float* out_b  = (const float*)d_in[8];
    float* yout = (float*)d_out;

    lstm_tr<<<B_SZ / ROWS, 64, 0, stream>>>(z, init_W, init_b, W_hh, b_ih, b_hh,
                                            out_W, out_b, yout);
}

// Round 7
// 666.371 us; speedup vs baseline: 1.2469x; 1.2469x over previous
//
#include <hip/hip_runtime.h>

// LSTMDecoder: B=4096, LATENT=128, SEQ=512, HID=32, OUT=64. f32 in/out.
// Round 7: sigma-permuted transposed recurrence (r6) + 4-wave split (r5) +
// transposed projection with dwordx4 stores + lgkm-only barrier + unroll x2.
//
//  - state fragment `a` (f16x8): lane(kb,n_) slot i=4jj+rr = h[n_][4kb+16jj+rr].
//    Serves as B for gates^T = W_hh @ h^T AND as B for y^T = out_W @ h^T.
//  - wave w (=2jj+p2): computes gate tiles {jj,2+jj,4+jj,6+jj} (dup per pair),
//    activations for regs r={2p2,2p2+1} -> cells 4kb+16jj+r, row n_ (lane-local,
//    20 transcendentals/lane/step). Writes packed u32 (2 halves) to hx[p][w][lane]
//    (conflict-free), barrier, all waves read 4 words -> next `a` in-lane.
//  - projection tile w: D reg r = out col 16w+4kb+r -> ONE global_store_dwordx4
//    per wave per step (4 consecutive cols of batch row n_).
//  - barrier = s_waitcnt lgkmcnt(0); s_barrier (no vmcnt drain: y stores stay
//    in flight). t-loop unrolled x2 so store data regs are recycled a full
//    step later (store latency hidden by issue + 3 sibling waves).

#define B_SZ   4096
#define LATENT 128
#define SEQ    512
#define HID    32
#define OUT_N  64
#define ROWS   16
#define LSW    40   // h0 staging row stride in halves (80 B rows)

typedef _Float16 f16x8 __attribute__((ext_vector_type(8)));
typedef _Float16 f16x4 __attribute__((ext_vector_type(4)));
typedef float    f32x4 __attribute__((ext_vector_type(4)));

__device__ __forceinline__ float fexp2(float x) { return __builtin_amdgcn_exp2f(x); }
__device__ __forceinline__ float frcp(float x)  { return __builtin_amdgcn_rcpf(x); }
__device__ __forceinline__ float sigm(float x) {
    return frcp(1.f + fexp2(-1.44269504088896341f * x));
}
__device__ __forceinline__ float tanh_f(float x) {
    return fmaf(-2.f, frcp(1.f + fexp2(2.88539008177792681f * x)), 1.f);
}
__device__ __forceinline__ void lds_barrier() {
    asm volatile("s_waitcnt lgkmcnt(0)\n\ts_barrier" ::: "memory");
}

__global__ __launch_bounds__(256)
void lstm_tr4(const float* __restrict__ z,
              const float* __restrict__ init_W,
              const float* __restrict__ init_b,
              const float* __restrict__ W_hh,
              const float* __restrict__ b_ih,
              const float* __restrict__ b_hh,
              const float* __restrict__ out_W,
              const float* __restrict__ out_b,
              float* __restrict__ y)
{
    __shared__ __align__(16) _Float16 hst[ROWS * LSW];
    __shared__ unsigned int hx[2][4][64];

    const int tid  = threadIdx.x;
    const int w    = tid >> 6;         // wave 0..3 (one per SIMD)
    const int lane = tid & 63;
    const int n_   = lane & 15;        // batch row within tile
    const int kb   = lane >> 4;        // k-group / D row-group
    const int jj   = w >> 1;           // cell half
    const int p2   = w & 1;            // reg pair
    const int rbase = blockIdx.x * ROWS;

    // ---- resident W_hh A-frags for this wave's 4 gate tiles (sigma-permuted k) ----
    // tile g: lane(kb,n_) slot i=4jj'+rr : W_hh[16g+n_][4kb+16jj'+rr]
    f16x8 wf[4];
    f32x4 bacc[4];
#pragma unroll
    for (int m = 0; m < 4; m++) {
        int g = 2 * m + jj;
        const float* row = W_hh + (size_t)(16 * g + n_) * HID;
        f16x8 v;
#pragma unroll
        for (int rr = 0; rr < 4; rr++) {
            v[rr]     = (_Float16)row[4 * kb + rr];
            v[4 + rr] = (_Float16)row[4 * kb + 16 + rr];
        }
        wf[m] = v;
        f32x4 b;
#pragma unroll
        for (int r = 0; r < 4; r++) {
            int G = 16 * g + 4 * kb + r;
            b[r] = b_ih[G] + b_hh[G];
        }
        bacc[m] = b;
    }
    // ---- proj A-frag: tile w (out cols 16w..16w+15), sigma-permuted k ----
    f16x8 owf;
    f32x4 oacc;
    {
        const float* row = out_W + (size_t)(16 * w + n_) * HID;
        f16x8 v;
#pragma unroll
        for (int rr = 0; rr < 4; rr++) {
            v[rr]     = (_Float16)row[4 * kb + rr];
            v[4 + rr] = (_Float16)row[4 * kb + 16 + rr];
        }
        owf = v;
#pragma unroll
        for (int r = 0; r < 4; r++) oacc[r] = out_b[16 * w + 4 * kb + r];
    }

    // ---- h0 = z @ init_W^T + init_b (cooperative, 2 cells/thread) ----
#pragma unroll
    for (int i = 0; i < 2; i++) {
        int e = tid + 256 * i;          // 0..511
        int m = e >> 5, j = e & 31;
        const float4* zp = (const float4*)(z + (size_t)(rbase + m) * LATENT);
        const float4* wp = (const float4*)(init_W + (size_t)j * LATENT);
        float acc = init_b[j];
#pragma unroll
        for (int k = 0; k < LATENT / 4; k++) {
            float4 a4 = zp[k], b4 = wp[k];
            acc = fmaf(a4.x, b4.x, acc); acc = fmaf(a4.y, b4.y, acc);
            acc = fmaf(a4.z, b4.z, acc); acc = fmaf(a4.w, b4.w, acc);
        }
        hst[m * LSW + j] = (_Float16)acc;
    }
    __syncthreads();

    // initial fragment: slot 4jj'+rr <- h0[n_][4kb+16jj'+rr]
    f16x8 a;
    {
        f16x4 lo = *(const f16x4*)&hst[n_ * LSW + 4 * kb];
        f16x4 hi = *(const f16x4*)&hst[n_ * LSW + 4 * kb + 16];
#pragma unroll
        for (int r = 0; r < 4; r++) { a[r] = lo[r]; a[4 + r] = hi[r]; }
    }

    float c2[2] = {0.f, 0.f};   // cells 4kb+16jj+2p2+{0,1}, row n_

    float* yb = y + (size_t)(rbase + n_) * SEQ * OUT_N + 16 * w + 4 * kb;

    for (int t = 0; t < SEQ; t += 2) {
#pragma unroll
        for (int u = 0; u < 2; u++) {
            // ---- gates (this wave's 4 tiles; duplicated across wave pair) ----
            f32x4 acc[4];
#pragma unroll
            for (int m = 0; m < 4; m++)
                acc[m] = __builtin_amdgcn_mfma_f32_16x16x32_f16(wf[m], a, bacc[m], 0, 0, 0);

            // ---- activations for this wave's 2 regs; pack 2 halves -> u32 ----
            unsigned int pk;
            {
                _Float16 hh[2];
#pragma unroll
                for (int r2 = 0; r2 < 2; r2++) {
                    int r = 2 * p2 + r2;
                    float gi = sigm(acc[0][r]);
                    float gf = sigm(acc[1][r]);
                    float gg = tanh_f(acc[2][r]);
                    float go = sigm(acc[3][r]);
                    float cn = fmaf(gf, c2[r2], gi * gg);
                    c2[r2] = cn;
                    hh[r2] = (_Float16)(go * tanh_f(cn));
                }
                union { _Float16 h[2]; unsigned int u32; } cv;
                cv.h[0] = hh[0]; cv.h[1] = hh[1];
                pk = cv.u32;
            }
            hx[u][w][lane] = pk;
            lds_barrier();

            // ---- gather next fragment: slot 2q+r2 <- half r2 of word q ----
            union { f16x8 v; unsigned int u32[4]; } nv;
#pragma unroll
            for (int q = 0; q < 4; q++) nv.u32[q] = hx[u][q][lane];
            a = nv.v;

            // ---- transposed projection: y[row n_][col 16w+4kb+r], r=0..3 ----
            f32x4 py = __builtin_amdgcn_mfma_f32_16x16x32_f16(owf, a, oacc, 0, 0, 0);
            *(f32x4*)(yb + (size_t)(t + u) * OUT_N) = py;
        }
    }
}

extern "C" void kernel_launch(void* const* d_in, const int* in_sizes, int n_in,
                              void* d_out, int out_size, void* d_ws, size_t ws_size,
                              hipStream_t stream) {
    const float* z      = (const float*)d_in[0];
    const float* init_W = (const float*)d_in[1];
    const float* init_b = (const float*)d_in[2];
    // d_in[3] = W_ih: unused (x input is all zeros; only biases survive)
    const float* W_hh   = (const float*)d_in[4];
    const float* b_ih   = (const float*)d_in[5];
    const float* b_hh   = (const float*)d_in[6];
    const float* out_W  = (const float*)d_in[7];
    const float* out_b  = (const float*)d_in[8];
    float* yout = (float*)d_out;

    lstm_tr4<<<B_SZ / ROWS, 256, 0, stream>>>(z, init_W, init_b, W_hh, b_ih, b_hh,
                                              out_W, out_b, yout);
}

// Round 8
// 635.334 us; speedup vs baseline: 1.3078x; 1.0489x over previous
//
#include <hip/hip_runtime.h>

// LSTMDecoder: B=4096, LATENT=128, SEQ=512, HID=32, OUT=64. f32 in/out.
// Round 8: 8 waves/block (2 per SIMD), 8-way activation split, unroll x4.
//
//  - sigma-permuted transposed recurrence (r6/r7): state frag `a` (f16x8):
//    lane(kb,n_) slot 4jj+rr = h[row n_][cell 4kb+16jj+rr]. B-operand for both
//    gates^T = W_hh @ h^T and y^T = out_W @ h^T.
//  - wave w: jj = w&1, r_ = w>>1 (0..3). Computes 4 gate MFMA tiles
//    {jj,2+jj,4+jj,6+jj} (duplicated across the 4 r-waves: matrix pipe ~2% busy,
//    duplication free) and activations for ONE cell/lane: cell 4kb+16jj+r_,
//    row n_ (10 transcendental instrs/lane/step = 80 cyc issue, was 160 in r7).
//  - exchange: ds_write_b16 -> hx[par][jj][lane][r_]; one lgkm-only barrier;
//    rebuild `a` with two ds_read_b64 (lane-stride 8 B = 2-way bank class, free).
//    hx alternates on u-parity => single barrier/step, no read/write race.
//  - projection: jj==0 waves own tile p=r_ -> one global_store_dwordx4/step.
//    t-loop unrolled x4 so store data regs recycle >=4 steps later (vmcnt depth
//    4 hides HBM store-ack).
//  - 2 waves/SIMD: co-resident waves interleave act-chain + LDS latency.

#define B_SZ   4096
#define LATENT 128
#define SEQ    512
#define HID    32
#define OUT_N  64
#define ROWS   16
#define LSW    40   // h0 staging row stride in halves (80 B rows)

typedef _Float16 f16x8 __attribute__((ext_vector_type(8)));
typedef _Float16 f16x4 __attribute__((ext_vector_type(4)));
typedef float    f32x4 __attribute__((ext_vector_type(4)));

__device__ __forceinline__ float fexp2(float x) { return __builtin_amdgcn_exp2f(x); }
__device__ __forceinline__ float frcp(float x)  { return __builtin_amdgcn_rcpf(x); }
__device__ __forceinline__ float sigm(float x) {
    return frcp(1.f + fexp2(-1.44269504088896341f * x));
}
__device__ __forceinline__ float tanh_f(float x) {
    return fmaf(-2.f, frcp(1.f + fexp2(2.88539008177792681f * x)), 1.f);
}
__device__ __forceinline__ void lds_barrier() {
    asm volatile("s_waitcnt lgkmcnt(0)\n\ts_barrier" ::: "memory");
}

__global__ __launch_bounds__(512)
void lstm_tr8(const float* __restrict__ z,
              const float* __restrict__ init_W,
              const float* __restrict__ init_b,
              const float* __restrict__ W_hh,
              const float* __restrict__ b_ih,
              const float* __restrict__ b_hh,
              const float* __restrict__ out_W,
              const float* __restrict__ out_b,
              float* __restrict__ y)
{
    __shared__ __align__(16) _Float16 hst[ROWS * LSW];
    __shared__ __align__(8) unsigned short hx[2][2][64][4];  // [par][jj][lane][r]

    const int tid  = threadIdx.x;
    const int w    = tid >> 6;          // wave 0..7
    const int lane = tid & 63;
    const int n_   = lane & 15;         // batch row within tile
    const int kb   = lane >> 4;         // k-group / D row-group
    const int jj   = w & 1;             // cell half
    const int r_   = w >> 1;            // D reg this wave activates (0..3)
    const int rbase = blockIdx.x * ROWS;

    // ---- resident W_hh A-frags for tiles {jj,2+jj,4+jj,6+jj} (sigma-permuted k) ----
    f16x8 wf[4];
    f32x4 bacc[4];
#pragma unroll
    for (int m = 0; m < 4; m++) {
        int g = 2 * m + jj;
        const float* row = W_hh + (size_t)(16 * g + n_) * HID;
        f16x8 v;
#pragma unroll
        for (int rr = 0; rr < 4; rr++) {
            v[rr]     = (_Float16)row[4 * kb + rr];
            v[4 + rr] = (_Float16)row[4 * kb + 16 + rr];
        }
        wf[m] = v;
        f32x4 b;
#pragma unroll
        for (int r = 0; r < 4; r++) {
            int G = 16 * g + 4 * kb + r;
            b[r] = b_ih[G] + b_hh[G];
        }
        bacc[m] = b;
    }
    // ---- proj A-frag (jj==0 waves own tile p=r_) ----
    f16x8 owf;
    f32x4 oacc;
    {
        int p = r_;
        const float* row = out_W + (size_t)(16 * p + n_) * HID;
        f16x8 v;
#pragma unroll
        for (int rr = 0; rr < 4; rr++) {
            v[rr]     = (_Float16)row[4 * kb + rr];
            v[4 + rr] = (_Float16)row[4 * kb + 16 + rr];
        }
        owf = v;
#pragma unroll
        for (int r = 0; r < 4; r++) oacc[r] = out_b[16 * p + 4 * kb + r];
    }

    // ---- h0 = z @ init_W^T + init_b (one cell per thread: 512 = 16x32) ----
    {
        int m = tid >> 5, j = tid & 31;
        const float4* zp = (const float4*)(z + (size_t)(rbase + m) * LATENT);
        const float4* wp = (const float4*)(init_W + (size_t)j * LATENT);
        float acc = init_b[j];
#pragma unroll
        for (int k = 0; k < LATENT / 4; k++) {
            float4 a4 = zp[k], b4 = wp[k];
            acc = fmaf(a4.x, b4.x, acc); acc = fmaf(a4.y, b4.y, acc);
            acc = fmaf(a4.z, b4.z, acc); acc = fmaf(a4.w, b4.w, acc);
        }
        hst[m * LSW + j] = (_Float16)acc;
    }
    __syncthreads();

    // initial fragment: slot 4jj'+rr <- h0[n_][4kb+16jj'+rr]
    f16x8 a;
    {
        f16x4 lo = *(const f16x4*)&hst[n_ * LSW + 4 * kb];
        f16x4 hi = *(const f16x4*)&hst[n_ * LSW + 4 * kb + 16];
#pragma unroll
        for (int r = 0; r < 4; r++) { a[r] = lo[r]; a[4 + r] = hi[r]; }
    }

    float c1 = 0.f;   // cell 4kb+16jj+r_, row n_

    float* yb = y + (size_t)(rbase + n_) * SEQ * OUT_N + 16 * r_ + 4 * kb;

    for (int t = 0; t < SEQ; t += 4) {
#pragma unroll
        for (int u = 0; u < 4; u++) {
            const int par = u & 1;
            // ---- gates (4 tiles, duplicated across r-waves) ----
            f32x4 acc[4];
#pragma unroll
            for (int m = 0; m < 4; m++)
                acc[m] = __builtin_amdgcn_mfma_f32_16x16x32_f16(wf[m], a, bacc[m], 0, 0, 0);

            // ---- activation for this wave's single cell ----
            {
                float gi = sigm(acc[0][r_]);
                float gf = sigm(acc[1][r_]);
                float gg = tanh_f(acc[2][r_]);
                float go = sigm(acc[3][r_]);
                float cn = fmaf(gf, c1, gi * gg);
                c1 = cn;
                union { _Float16 h; unsigned short u16; } cv;
                cv.h = (_Float16)(go * tanh_f(cn));
                hx[par][jj][lane][r_] = cv.u16;
            }
            lds_barrier();

            // ---- rebuild fragment: two b64 reads, in-lane ----
            f16x4 lo = *(const f16x4*)&hx[par][0][lane][0];
            f16x4 hi = *(const f16x4*)&hx[par][1][lane][0];
#pragma unroll
            for (int r = 0; r < 4; r++) { a[r] = lo[r]; a[4 + r] = hi[r]; }

            // ---- projection (jj==0 waves): y[row n_][cols 16r_+4kb .. +3] ----
            if (jj == 0) {
                f32x4 py = __builtin_amdgcn_mfma_f32_16x16x32_f16(owf, a, oacc, 0, 0, 0);
                *(f32x4*)(yb + (size_t)(t + u) * OUT_N) = py;
            }
        }
    }
}

extern "C" void kernel_launch(void* const* d_in, const int* in_sizes, int n_in,
                              void* d_out, int out_size, void* d_ws, size_t ws_size,
                              hipStream_t stream) {
    const float* z      = (const float*)d_in[0];
    const float* init_W = (const float*)d_in[1];
    const float* init_b = (const float*)d_in[2];
    // d_in[3] = W_ih: unused (x input is all zeros; only biases survive)
    const float* W_hh   = (const float*)d_in[4];
    const float* b_ih   = (const float*)d_in[5];
    const float* b_hh   = (const float*)d_in[6];
    const float* out_W  = (const float*)d_in[7];
    const float* out_b  = (const float*)d_in[8];
    float* yout = (float*)d_out;

    lstm_tr8<<<B_SZ / ROWS, 512, 0, stream>>>(z, init_W, init_b, W_hh, b_ih, b_hh,
                                              out_W, out_b, yout);
}